// Round 1
// baseline (1231.549 us; speedup 1.0000x reference)
//
#include <hip/hip_runtime.h>

typedef __attribute__((ext_vector_type(4))) float  f32x4;
typedef __attribute__((ext_vector_type(8))) short  short8;
typedef unsigned short ushort_t;

#define MM   8192
#define FEATD 2048
#define KC   256
#define NKE  (MM*KC)        // 2097152 elements per [N,K] slab

struct InP { const float* p[25]; };

__device__ __forceinline__ unsigned short f2bf(float f){
    union { __bf16 b; unsigned short u; } c;
    c.b = (__bf16)f;
    return c.u;
}

__device__ __forceinline__ float act1(float u, float th){
    const float lam = 1.0507009873554805f;
    const float la  = 1.7580993408473766f;   // lam * alpha_selu
    float x = u - th;
    float s1 = (x > 0.f) ? lam * x : la * (__expf(x) - 1.f);
    float y = -u - th;
    float s2 = (y > 0.f) ? lam * y : la * (__expf(y) - 1.f);
    return s1 - s2;
}

__device__ __forceinline__ void gl2lds16(const void* g, void* l){
    __builtin_amdgcn_global_load_lds(
        (const __attribute__((address_space(1))) unsigned int*)g,
        (__attribute__((address_space(3))) unsigned int*)l, 16, 0, 0);
}

// ---------------------------------------------------------------------------
// Kernel W: convert small weights fp32 -> bf16 in ws.
// WU[j] = [Wz[j] ; Uw[j]]  (512 x 2048), Swb[j] = Sw[j] (256 x 256)
// ---------------------------------------------------------------------------
__global__ void kW(InP in, ushort_t* WU, ushort_t* Swb){
    int idx = blockIdx.x * 256 + threadIdx.x;           // pair index
    const int WUP = 3 * 512 * 1024;                     // WU pairs
    const int SWP = 3 * 32768;                          // Sw pairs
    if (idx < WUP){
        int j   = idx / (512 * 1024);
        int rem = idx - j * (512 * 1024);
        int r   = rem >> 10;          // row 0..511
        int kp  = rem & 1023;         // pair in row
        const float* src = (r < 256) ? in.p[8*j+2] + (size_t)r*FEATD + kp*2
                                     : in.p[8*j+6] + (size_t)(r-256)*FEATD + kp*2;
        float2 v = *(const float2*)src;
        ushort_t* dst = WU + (size_t)j*512*FEATD + (size_t)r*FEATD + kp*2;
        dst[0] = f2bf(v.x); dst[1] = f2bf(v.y);
    } else if (idx < WUP + SWP){
        int t   = idx - WUP;
        int j   = t / 32768;
        int rem = t - j * 32768;
        const float* src = in.p[8*j+4] + (size_t)rem*2;
        float2 v = *(const float2*)src;
        ushort_t* dst = Swb + (size_t)j*KC*KC + (size_t)rem*2;
        dst[0] = f2bf(v.x); dst[1] = f2bf(v.y);
    }
}

// ---------------------------------------------------------------------------
// Kernel A: per view j, C = f @ [Wz|Uw]^T  (M=8192, K=2048, N=512)
// 2-phase double-buffered pipeline: one barrier per K-step; loads for tile
// t+1 issued before MFMA of tile t (latency hidden under compute).
// ---------------------------------------------------------------------------
__global__ __launch_bounds__(256, 3)
void kA(InP in, const ushort_t* WU, float* out, ushort_t* Zt, ushort_t* Zn, float* P){
    const int bn = blockIdx.x, bm = blockIdx.y, j = blockIdx.z;
    const float* f  = in.p[8*j+0];
    const float* bz = in.p[8*j+3];
    const float* Ub = in.p[8*j+7];
    const float  th = in.p[24][0];
    const ushort_t* WUj = WU + (size_t)j*512*FEATD;

    __shared__ ushort_t Al[2][128*32] __attribute__((aligned(16)));
    __shared__ ushort_t Bl[2][128*32] __attribute__((aligned(16)));

    const int tid = threadIdx.x, lane = tid & 63, wave = tid >> 6;
    const int wm = wave >> 1, wn = wave & 1;

    f32x4 acc[4][4] = {};

    // A staging: thread t loads 16 fp32 of row (t>>1), half (t&1)
    const int sm = tid >> 1, sh = tid & 1;
    const float* gA = f + (size_t)(bm*128 + sm)*FEATD + sh*16;
    const int lAoff = sm*32 + sh*16;
    // B staging via global_load_lds (bf16 already): linear lane*16B layout
    const ushort_t* gB = WUj + (size_t)(bn*128 + (tid>>2))*FEATD + (tid&3)*8;
    const int lBoff = tid*8;

    const int fAoff = (wm*64 + (lane&15))*32 + (lane>>4)*8;
    const int fBoff = (wn*64 + (lane&15))*32 + (lane>>4)*8;

    // prologue: stage tile 0 into buffer 0
    {
        float4 v0 = *(const float4*)(gA);
        float4 v1 = *(const float4*)(gA + 4);
        float4 v2 = *(const float4*)(gA + 8);
        float4 v3 = *(const float4*)(gA + 12);
        gl2lds16(gB,            &Bl[0][lBoff]);
        gl2lds16(gB + 64*FEATD, &Bl[0][lBoff + 64*32]);
        short8 w0, w1;
        w0[0]=(short)f2bf(v0.x); w0[1]=(short)f2bf(v0.y); w0[2]=(short)f2bf(v0.z); w0[3]=(short)f2bf(v0.w);
        w0[4]=(short)f2bf(v1.x); w0[5]=(short)f2bf(v1.y); w0[6]=(short)f2bf(v1.z); w0[7]=(short)f2bf(v1.w);
        w1[0]=(short)f2bf(v2.x); w1[1]=(short)f2bf(v2.y); w1[2]=(short)f2bf(v2.z); w1[3]=(short)f2bf(v2.w);
        w1[4]=(short)f2bf(v3.x); w1[5]=(short)f2bf(v3.y); w1[6]=(short)f2bf(v3.z); w1[7]=(short)f2bf(v3.w);
        *(short8*)&Al[0][lAoff]     = w0;
        *(short8*)&Al[0][lAoff + 8] = w1;
        gA += 32; gB += 32;
    }
    __syncthreads();

    #pragma unroll 1
    for (int kt = 0; kt < FEATD/32 - 1; ++kt){
        const int cur = kt & 1, nxt = cur ^ 1;
        // issue next tile's loads first (overlap with MFMA below)
        float4 v0 = *(const float4*)(gA);
        float4 v1 = *(const float4*)(gA + 4);
        float4 v2 = *(const float4*)(gA + 8);
        float4 v3 = *(const float4*)(gA + 12);
        gl2lds16(gB,            &Bl[nxt][lBoff]);
        gl2lds16(gB + 64*FEATD, &Bl[nxt][lBoff + 64*32]);
        gA += 32; gB += 32;

        short8 afr[4], bfr[4];
        #pragma unroll
        for (int mf = 0; mf < 4; ++mf) afr[mf] = *(const short8*)&Al[cur][fAoff + mf*16*32];
        #pragma unroll
        for (int nf = 0; nf < 4; ++nf) bfr[nf] = *(const short8*)&Bl[cur][fBoff + nf*16*32];
        #pragma unroll
        for (int mf = 0; mf < 4; ++mf)
            #pragma unroll
            for (int nf = 0; nf < 4; ++nf)
                acc[mf][nf] = __builtin_amdgcn_mfma_f32_16x16x32_bf16(afr[mf], bfr[nf], acc[mf][nf], 0, 0, 0);

        // convert + write A(t+1) after MFMA (vmcnt wait lands here, hidden)
        short8 w0, w1;
        w0[0]=(short)f2bf(v0.x); w0[1]=(short)f2bf(v0.y); w0[2]=(short)f2bf(v0.z); w0[3]=(short)f2bf(v0.w);
        w0[4]=(short)f2bf(v1.x); w0[5]=(short)f2bf(v1.y); w0[6]=(short)f2bf(v1.z); w0[7]=(short)f2bf(v1.w);
        w1[0]=(short)f2bf(v2.x); w1[1]=(short)f2bf(v2.y); w1[2]=(short)f2bf(v2.z); w1[3]=(short)f2bf(v2.w);
        w1[4]=(short)f2bf(v3.x); w1[5]=(short)f2bf(v3.y); w1[6]=(short)f2bf(v3.z); w1[7]=(short)f2bf(v3.w);
        *(short8*)&Al[nxt][lAoff]     = w0;
        *(short8*)&Al[nxt][lAoff + 8] = w1;
        __syncthreads();
    }
    { // final tile (index FEATD/32-1 = 63, cur = 1)
        const int cur = (FEATD/32 - 1) & 1;
        short8 afr[4], bfr[4];
        #pragma unroll
        for (int mf = 0; mf < 4; ++mf) afr[mf] = *(const short8*)&Al[cur][fAoff + mf*16*32];
        #pragma unroll
        for (int nf = 0; nf < 4; ++nf) bfr[nf] = *(const short8*)&Bl[cur][fBoff + nf*16*32];
        #pragma unroll
        for (int mf = 0; mf < 4; ++mf)
            #pragma unroll
            for (int nf = 0; nf < 4; ++nf)
                acc[mf][nf] = __builtin_amdgcn_mfma_f32_16x16x32_bf16(afr[mf], bfr[nf], acc[mf][nf], 0, 0, 0);
    }

    // epilogue (unchanged)
    #pragma unroll
    for (int mf = 0; mf < 4; ++mf){
        #pragma unroll
        for (int nf = 0; nf < 4; ++nf){
            int m_b = bm*128 + wm*64 + mf*16 + ((lane>>4)<<2);
            int c   = bn*128 + wn*64 + nf*16 + (lane&15);
            f32x4 a4 = acc[mf][nf];
            if (c < 256){
                float bias = bz[c];
                float z0 = act1(a4[0]+bias, th), z1 = act1(a4[1]+bias, th);
                float z2 = act1(a4[2]+bias, th), z3 = act1(a4[3]+bias, th);
                float* oz = out + (size_t)j*NKE + (size_t)m_b*KC + c;
                float* oa = out + (size_t)(10+j)*NKE + (size_t)m_b*KC + c;
                oz[0]=z0; oz[KC]=z1; oz[2*KC]=z2; oz[3*KC]=z3;
                oa[0]=z0+1.f; oa[KC]=z1+1.f; oa[2*KC]=z2+1.f; oa[3*KC]=z3+1.f;
                ushort4 zt; zt.x=f2bf(z0); zt.y=f2bf(z1); zt.z=f2bf(z2); zt.w=f2bf(z3);
                *(ushort4*)(Zt + (size_t)j*KC*MM + (size_t)c*MM + m_b) = zt;
                ushort_t* zn = Zn + (size_t)j*MM*KC + (size_t)m_b*KC + c;
                zn[0]=zt.x; zn[KC]=zt.y; zn[2*KC]=zt.z; zn[3*KC]=zt.w;
            } else {
                float bias = Ub[c-256];
                float* pp = P + (size_t)j*NKE + (size_t)m_b*KC + (c-256);
                pp[0]=a4[0]+bias; pp[KC]=a4[1]+bias; pp[2*KC]=a4[2]+bias; pp[3*KC]=a4[3]+bias;
            }
        }
    }
}

// ---------------------------------------------------------------------------
// Kernel B: per view j, partial = (-gamma*lap) @ Z  (+ Z @ Sw^T on chunk 0)
// 2-phase double-buffered pipeline, one barrier per K-step.
// -gamma folded into the fp32->bf16 staging conversion of lap.
// ---------------------------------------------------------------------------
__global__ __launch_bounds__(256, 3)
void kB(InP in, const ushort_t* Zt, const ushort_t* Zn, const ushort_t* Swb, float* part){
    const int chunk = blockIdx.x, bm = blockIdx.y, j = blockIdx.z;
    const float* lap = in.p[8*j+1];
    const ushort_t* Ztj = Zt + (size_t)j*KC*MM;

    __shared__ ushort_t Al[2][64*32]  __attribute__((aligned(16)));
    __shared__ ushort_t Bl[2][256*32] __attribute__((aligned(16)));

    const int tid = threadIdx.x, lane = tid & 63, wn = tid >> 6;

    f32x4 acc[4][4] = {};

    const int sm = tid >> 2, sh = tid & 3;
    const float* gA = lap + (size_t)(bm*64 + sm)*MM + chunk*4096 + sh*8;
    const int lAoff = sm*32 + sh*8;
    const ushort_t* gB = Ztj + (size_t)(tid>>2)*MM + chunk*4096 + (tid&3)*8;
    const int lBoff = tid*8;

    const int fAoff = (lane&15)*32 + (lane>>4)*8;
    const int fBoff = (wn*64 + (lane&15))*32 + (lane>>4)*8;

    // prologue: stage tile 0 into buffer 0
    {
        float4 v0 = *(const float4*)(gA);
        float4 v1 = *(const float4*)(gA + 4);
        gl2lds16(gB,            &Bl[0][lBoff]);
        gl2lds16(gB +  64*MM,   &Bl[0][lBoff +  64*32]);
        gl2lds16(gB + 128*MM,   &Bl[0][lBoff + 128*32]);
        gl2lds16(gB + 192*MM,   &Bl[0][lBoff + 192*32]);
        short8 w;
        w[0]=(short)f2bf(v0.x*-0.5f); w[1]=(short)f2bf(v0.y*-0.5f);
        w[2]=(short)f2bf(v0.z*-0.5f); w[3]=(short)f2bf(v0.w*-0.5f);
        w[4]=(short)f2bf(v1.x*-0.5f); w[5]=(short)f2bf(v1.y*-0.5f);
        w[6]=(short)f2bf(v1.z*-0.5f); w[7]=(short)f2bf(v1.w*-0.5f);
        *(short8*)&Al[0][lAoff] = w;
        gA += 32; gB += 32;
    }
    __syncthreads();

    #pragma unroll 1
    for (int kt = 0; kt < 127; ++kt){
        const int cur = kt & 1, nxt = cur ^ 1;
        float4 v0 = *(const float4*)(gA);
        float4 v1 = *(const float4*)(gA + 4);
        gl2lds16(gB,            &Bl[nxt][lBoff]);
        gl2lds16(gB +  64*MM,   &Bl[nxt][lBoff +  64*32]);
        gl2lds16(gB + 128*MM,   &Bl[nxt][lBoff + 128*32]);
        gl2lds16(gB + 192*MM,   &Bl[nxt][lBoff + 192*32]);
        gA += 32; gB += 32;

        short8 afr[4], bfr[4];
        #pragma unroll
        for (int mf = 0; mf < 4; ++mf) afr[mf] = *(const short8*)&Al[cur][fAoff + mf*16*32];
        #pragma unroll
        for (int nf = 0; nf < 4; ++nf) bfr[nf] = *(const short8*)&Bl[cur][fBoff + nf*16*32];
        #pragma unroll
        for (int mf = 0; mf < 4; ++mf)
            #pragma unroll
            for (int nf = 0; nf < 4; ++nf)
                acc[mf][nf] = __builtin_amdgcn_mfma_f32_16x16x32_bf16(afr[mf], bfr[nf], acc[mf][nf], 0, 0, 0);

        short8 w;
        w[0]=(short)f2bf(v0.x*-0.5f); w[1]=(short)f2bf(v0.y*-0.5f);
        w[2]=(short)f2bf(v0.z*-0.5f); w[3]=(short)f2bf(v0.w*-0.5f);
        w[4]=(short)f2bf(v1.x*-0.5f); w[5]=(short)f2bf(v1.y*-0.5f);
        w[6]=(short)f2bf(v1.z*-0.5f); w[7]=(short)f2bf(v1.w*-0.5f);
        *(short8*)&Al[nxt][lAoff] = w;
        __syncthreads();
    }
    { // final tile (index 127, cur = 1)
        const int cur = 1;
        short8 afr[4], bfr[4];
        #pragma unroll
        for (int mf = 0; mf < 4; ++mf) afr[mf] = *(const short8*)&Al[cur][fAoff + mf*16*32];
        #pragma unroll
        for (int nf = 0; nf < 4; ++nf) bfr[nf] = *(const short8*)&Bl[cur][fBoff + nf*16*32];
        #pragma unroll
        for (int mf = 0; mf < 4; ++mf)
            #pragma unroll
            for (int nf = 0; nf < 4; ++nf)
                acc[mf][nf] = __builtin_amdgcn_mfma_f32_16x16x32_bf16(afr[mf], bfr[nf], acc[mf][nf], 0, 0, 0);
    }

    if (chunk == 0){
        // fold in Z @ Sw^T : 8 iterations over the class dim (256), buffer 0
        const ushort_t* gA2 = Zn + (size_t)j*MM*KC + (size_t)(bm*64 + (tid>>2))*KC + (tid&3)*8;
        const ushort_t* gB2 = Swb + (size_t)j*KC*KC + (size_t)(tid>>2)*KC + (tid&3)*8;
        #pragma unroll 1
        for (int kt = 0; kt < 8; ++kt){
            __syncthreads();
            gl2lds16(gA2, &Al[0][lAoff & 0x7ff]);          // same map as main A: (tid>>2)*32+(tid&3)*8
            gl2lds16(gB2,           &Bl[0][lBoff]);
            gl2lds16(gB2 +  64*KC,  &Bl[0][lBoff +  64*32]);
            gl2lds16(gB2 + 128*KC,  &Bl[0][lBoff + 128*32]);
            gl2lds16(gB2 + 192*KC,  &Bl[0][lBoff + 192*32]);
            __syncthreads();
            short8 afr[4], bfr[4];
            #pragma unroll
            for (int mf = 0; mf < 4; ++mf) afr[mf] = *(const short8*)&Al[0][fAoff + mf*16*32];
            #pragma unroll
            for (int nf = 0; nf < 4; ++nf) bfr[nf] = *(const short8*)&Bl[0][fBoff + nf*16*32];
            #pragma unroll
            for (int mf = 0; mf < 4; ++mf)
                #pragma unroll
                for (int nf = 0; nf < 4; ++nf)
                    acc[mf][nf] = __builtin_amdgcn_mfma_f32_16x16x32_bf16(afr[mf], bfr[nf], acc[mf][nf], 0, 0, 0);
            gA2 += 32; gB2 += 32;
        }
    }

    #pragma unroll
    for (int mf = 0; mf < 4; ++mf){
        #pragma unroll
        for (int nf = 0; nf < 4; ++nf){
            int m = bm*64 + mf*16 + ((lane>>4)<<2);
            int c = wn*64 + nf*16 + (lane&15);
            float* pp = part + ((size_t)(chunk*3 + j)*MM + m)*KC + c;
            f32x4 a4 = acc[mf][nf];
            pp[0]=a4[0]; pp[KC]=a4[1]; pp[2*KC]=a4[2]; pp[3*KC]=a4[3];
        }
    }
}

// ---------------------------------------------------------------------------
// Kernel C: H = P + part0 + part1 + Sb ; A = act(H); write A to out slots;
// elementwise DS fold: e_new = e1 + e2 + e1*e2/K  (algebraic simplification)
// ---------------------------------------------------------------------------
__device__ __forceinline__ void comb4(float4& e, const float4 b){
    const float ik = 1.0f/256.0f;
    e.x = e.x + b.x + e.x*b.x*ik;
    e.y = e.y + b.y + e.y*b.y*ik;
    e.z = e.z + b.z + e.z*b.z*ik;
    e.w = e.w + b.w + e.w*b.w*ik;
}

__global__ void kC(InP in, const float* P, const float* part, float* out){
    const size_t base = ((size_t)blockIdx.x * 256 + threadIdx.x) * 4;
    const int k = (int)(base & (KC-1));
    const float th = in.p[24][0];

    float4 z0 = *(const float4*)(out + base);
    float4 z1 = *(const float4*)(out + (size_t)NKE + base);
    float4 z2 = *(const float4*)(out + (size_t)2*NKE + base);

    float4 A[3];
    #pragma unroll
    for (int j = 0; j < 3; ++j){
        float4 p  = *(const float4*)(P    + (size_t)j*NKE + base);
        float4 q0 = *(const float4*)(part + (size_t)j*NKE + base);
        float4 q1 = *(const float4*)(part + (size_t)(3+j)*NKE + base);
        float4 sb = *(const float4*)(in.p[8*j+5] + k);
        float4 h;
        h.x = p.x + q0.x + q1.x + sb.x;
        h.y = p.y + q0.y + q1.y + sb.y;
        h.z = p.z + q0.z + q1.z + sb.z;
        h.w = p.w + q0.w + q1.w + sb.w;
        float4 a;
        a.x = act1(h.x, th); a.y = act1(h.y, th);
        a.z = act1(h.z, th); a.w = act1(h.w, th);
        A[j] = a;
        *(float4*)(out + (size_t)(3+j)*NKE + base) = a;
        *(float4*)(out + (size_t)(6+j)*NKE + base) = a;
        float4 ap; ap.x=a.x+1.f; ap.y=a.y+1.f; ap.z=a.z+1.f; ap.w=a.w+1.f;
        *(float4*)(out + (size_t)(13+j)*NKE + base) = ap;
        *(float4*)(out + (size_t)(16+j)*NKE + base) = ap;
    }

    float4 e = z0;
    comb4(e, z1); comb4(e, z2);
    comb4(e, A[0]); comb4(e, A[1]); comb4(e, A[2]);
    comb4(e, A[0]); comb4(e, A[1]); comb4(e, A[2]);

    *(float4*)(out + (size_t)9*NKE + base) = e;          // evi = alpha - 1
    float4 al; al.x=e.x+1.f; al.y=e.y+1.f; al.z=e.z+1.f; al.w=e.w+1.f;
    *(float4*)(out + (size_t)19*NKE + base) = al;        // alpha
}

// ---------------------------------------------------------------------------
extern "C" void kernel_launch(void* const* d_in, const int* in_sizes, int n_in,
                              void* d_out, int out_size, void* d_ws, size_t ws_size,
                              hipStream_t stream){
    InP in;
    for (int i = 0; i < 25; ++i) in.p[i] = (const float*)d_in[i];

    char* w = (char*)d_ws;
    ushort_t* WU  = (ushort_t*)w;                       // 3*512*2048 bf16
    ushort_t* Swb = WU  + (size_t)3*512*FEATD;          // 3*256*256 bf16
    ushort_t* Zt  = Swb + (size_t)3*KC*KC;              // 3*256*8192 bf16 (Z^T)
    ushort_t* Zn  = Zt  + (size_t)3*KC*MM;              // 3*8192*256 bf16 (Z)
    float*    P   = (float*)(Zn + (size_t)3*MM*KC);     // 3*8192*256 fp32
    float*    part= P + (size_t)3*NKE;                  // 2*3*8192*256 fp32

    float* out = (float*)d_out;

    hipLaunchKernelGGL(kW, dim3(6528),     dim3(256), 0, stream, in, WU, Swb);
    hipLaunchKernelGGL(kA, dim3(4, 64, 3), dim3(256), 0, stream, in, WU, out, Zt, Zn, P);
    hipLaunchKernelGGL(kB, dim3(2, 128, 3),dim3(256), 0, stream, in, Zt, Zn, Swb, part);
    hipLaunchKernelGGL(kC, dim3(2048),     dim3(256), 0, stream, in, P, part, out);
}